// Round 9
// baseline (319.686 us; speedup 1.0000x reference)
//
#include <hip/hip_runtime.h>
#include <hip/hip_cooperative_groups.h>
#include <stdint.h>

namespace cg = cooperative_groups;

// Problem constants (B=4, S=2048 -> M = 8192 rows)
#define M_TOT 8192
#define N_TOT 4096
#define K_TOT 4096

typedef int v4i __attribute__((ext_vector_type(4)));

// GEMM tile config: 256x256 tile, sub-tile K-step = 64 B, 8 waves (2M x 4N)
#define BM 256
#define BN 256
#define SUB 64
#define NS (K_TOT / SUB)                  // 64 sub-tile iterations
#define A_SUB (BM * SUB)                  // 16 KB
#define B_SUB (BN * SUB)                  // 16 KB
#define BUF_BYTES (A_SUB + B_SUB)         // 32 KB; x4 buffers = 128 KB LDS

// ---------------------------------------------------------------------------
// Kernel 1 (cooperative): pack w int32->int8, global max(|x/s|), grid sync,
// then quantize x -> int8. One kernel = no inter-kernel drain/relaunch gap.
// 1024 blocks x 256 thr = 4 blocks/CU (co-residency safe at this VGPR count).
// Grid stride 262144 is a multiple of K/4=1024 -> smooth slice loop-invariant.
// ---------------------------------------------------------------------------
__global__ void prep_all(const int4* __restrict__ w32, int* __restrict__ w8,
                         int nw4, const float4* __restrict__ smooth4,
                         const float4* __restrict__ x,
                         unsigned int* __restrict__ maxbits, int nx4,
                         int* __restrict__ xq) {
  const int stride = gridDim.x * blockDim.x;
  const int g0 = blockIdx.x * blockDim.x + threadIdx.x;
  // ---- pack weights ----
  for (int i = g0; i < nw4; i += stride) {
    int4 v = w32[i];
    w8[i] = (v.x & 0xff) | ((v.y & 0xff) << 8) | ((v.z & 0xff) << 16) | (v.w << 24);
  }
  // ---- max-abs reduce with hoisted reciprocal ----
  float4 s = smooth4[g0 & (K_TOT / 4 - 1)];
  const float rx = 1.0f / s.x, ry = 1.0f / s.y, rz = 1.0f / s.z, rw = 1.0f / s.w;
  float m = 0.0f;
  for (int i = g0; i < nx4; i += stride) {
    float4 v = x[i];
    m = fmaxf(m, fabsf(v.x * rx));
    m = fmaxf(m, fabsf(v.y * ry));
    m = fmaxf(m, fabsf(v.z * rz));
    m = fmaxf(m, fabsf(v.w * rw));
  }
#pragma unroll
  for (int off = 32; off; off >>= 1) m = fmaxf(m, __shfl_xor(m, off));
  __shared__ float sm[4];
  if ((threadIdx.x & 63) == 0) sm[threadIdx.x >> 6] = m;
  __syncthreads();
  if (threadIdx.x == 0) {
    float mm = fmaxf(fmaxf(sm[0], sm[1]), fmaxf(sm[2], sm[3]));
    atomicMax(maxbits, __float_as_uint(mm));
    __threadfence();
  }
  cg::this_grid().sync();
  // ---- read scale (device-coherent via atomic read), broadcast via LDS ----
  __shared__ float s_inv;
  if (threadIdx.x == 0) {
    unsigned mb = atomicOr(maxbits, 0u);
    s_inv = 1.0f / (__uint_as_float(mb) / 127.0f + 1e-5f);
  }
  __syncthreads();
  const float inv = s_inv;
  const float qx = inv / s.x, qy = inv / s.y, qz = inv / s.z, qw = inv / s.w;
  // ---- quantize ----
  for (int i = g0; i < nx4; i += stride) {
    float4 v = x[i];
    int q0 = (int)fminf(fmaxf(rintf(v.x * qx), -128.0f), 127.0f);
    int q1 = (int)fminf(fmaxf(rintf(v.y * qy), -128.0f), 127.0f);
    int q2 = (int)fminf(fmaxf(rintf(v.z * qz), -128.0f), 127.0f);
    int q3 = (int)fminf(fmaxf(rintf(v.w * qw), -128.0f), 127.0f);
    xq[i] = (q0 & 0xff) | ((q1 & 0xff) << 8) | ((q2 & 0xff) << 16) | (q3 << 24);
  }
}

// ---------------------------------------------------------------------------
// Kernel 2: int8 GEMM — R6 VERBATIM (verified: 136.5 us, MfmaUtil 44%,
// SQ_LDS_BANK_CONFLICT == 0). 256x256 tile, 64-B K-sub-tiles, 4-buffer /
// 3-deep counted-vmcnt pipeline, ONE barrier per sub-tile.
//
// Race-freedom (iteration s, reading buf[s&3]):
//   * stage targets buf[(s+3)&3] = buf[(s-1)&3]: reads completed before iter
//     s-1's end barrier (lgkmcnt(0) precedes it). -> no write-under-read.
//   * vmcnt(8) at iter s end: outstanding = 12 (s, s-1, s-2); completing to 8
//     drains the OLDEST 4 = sub-tile s+1's loads; barrier makes that global.
//     Induction base: prologue stages 0,1,2 then vmcnt(8) drains sub-tile 0.
//   * vmcnt never drains to 0 in the loop (T4).
//
// LDS swizzle (T2, 64-B rows, 8-lane ds_read_b128 grouping) — MEASURED 0:
//   read slot = (lhi ^ ((l16>>1)&3))*16; stage gcol = ((lane&3)^((lane>>3)&3))*16
// (R5's l16>>2 variant and R7's 32-row variant both measured 1.26e7 — do not
//  touch this pattern without a measured-zero replacement.)
// ---------------------------------------------------------------------------
__global__ __launch_bounds__(512, 2) void gemm_i8(
    const int8_t* __restrict__ Aq,   // [M][K]
    const int8_t* __restrict__ Wt,   // [N][K]
    const unsigned int* __restrict__ maxbits,
    const float* __restrict__ wscale,  // [N]
    const float* __restrict__ bias,    // [N]
    float* __restrict__ out) {         // [M][N]
  __shared__ int8_t lds[4 * BUF_BYTES];

  const int tid = threadIdx.x;
  const int lane = tid & 63;
  const int wid = tid >> 6;      // 0..7
  const int l16 = lane & 15;
  const int lhi = lane >> 4;     // 0..3

  // T1: XCD-aware block swizzle. 512 blocks, 512 % 8 == 0 -> bijective.
  const int flat = blockIdx.y * gridDim.x + blockIdx.x;
  const int swz = (flat & 7) * 64 + (flat >> 3);
  const int m0 = (swz / (N_TOT / BN)) * BM;
  const int n0 = (swz % (N_TOT / BN)) * BN;

  const int wave_m = wid >> 2;   // 0..1  -> 128 rows
  const int wave_n = wid & 3;    // 0..3  -> 64 cols

  // ---- staging: per wave 2 A-chunks + 2 B-chunks, 1 KB each (16 rows x 64 B)
  const int row_l = lane >> 2;                             // row in chunk 0..15
  const int gcol = ((lane & 3) ^ ((lane >> 3) & 3)) << 4;  // pre-swizzled slot
  const int8_t* Abase = Aq + (size_t)m0 * K_TOT;           // uniform
  const int8_t* Bbase = Wt + (size_t)n0 * K_TOT;           // uniform
  int goff[2];
#pragma unroll
  for (int c = 0; c < 2; ++c) {
    int grow = (wid * 2 + c) * 16 + row_l;                 // 0..255
    goff[c] = grow * K_TOT + gcol;
  }

  auto stage = [&](int dstbuf, int koff) {
#pragma unroll
    for (int c = 0; c < 2; ++c) {
      __builtin_amdgcn_global_load_lds(
          (const __attribute__((address_space(1))) void*)(Abase + goff[c] + koff),
          (__attribute__((address_space(3))) void*)(lds + dstbuf * BUF_BYTES + (wid * 2 + c) * 1024),
          16, 0, 0);
      __builtin_amdgcn_global_load_lds(
          (const __attribute__((address_space(1))) void*)(Bbase + goff[c] + koff),
          (__attribute__((address_space(3))) void*)(lds + dstbuf * BUF_BYTES + A_SUB + (wid * 2 + c) * 1024),
          16, 0, 0);
    }
  };

  // ---- ds_read fragment addressing (swizzled, 64-B rows) ----
  const int slot = (lhi ^ ((l16 >> 1) & 3)) << 4;
  const int aOff = (wave_m * 128 + l16) * SUB + slot;
  const int bOff = (wave_n * 64 + l16) * SUB + slot;

  // ---- prologue: stage sub-tiles 0,1,2; drain sub-tile 0 ----
  stage(0, 0);
  stage(1, SUB);
  stage(2, 2 * SUB);
  asm volatile("s_waitcnt vmcnt(8)" ::: "memory");
  __builtin_amdgcn_s_barrier();
  __builtin_amdgcn_sched_barrier(0);

  v4i acc[8][4] = {};

#pragma unroll 4
  for (int s = 0; s < NS; ++s) {
    const int buf = s & 3;
    const int8_t* Ab = lds + buf * BUF_BYTES;
    const int8_t* Bb = Ab + A_SUB;

    // prefetch sub-tile s+3 into the buffer drained at iter s-1
    const int ts = (s + 3 < NS) ? (s + 3) : (NS - 1);
    stage((s + 3) & 3, ts * SUB);

    // 12 ds_read_b128; compiler-counted lgkmcnt lets MFMA overlap them
    v4i a[8], b[4];
#pragma unroll
    for (int i = 0; i < 8; ++i) a[i] = *(const v4i*)(Ab + aOff + i * 1024);
#pragma unroll
    for (int j = 0; j < 4; ++j) b[j] = *(const v4i*)(Bb + bOff + j * 1024);

    __builtin_amdgcn_s_setprio(1);
#pragma unroll
    for (int i = 0; i < 8; ++i)
#pragma unroll
      for (int j = 0; j < 4; ++j)
        acc[i][j] = __builtin_amdgcn_mfma_i32_16x16x64_i8(a[i], b[j], acc[i][j], 0, 0, 0);
    __builtin_amdgcn_s_setprio(0);
    __builtin_amdgcn_sched_barrier(0);

    asm volatile("s_waitcnt lgkmcnt(0)" ::: "memory");
    asm volatile("s_waitcnt vmcnt(8)" ::: "memory");
    __builtin_amdgcn_sched_barrier(0);
    __builtin_amdgcn_s_barrier();
    __builtin_amdgcn_sched_barrier(0);
  }

  // ---- epilogue: dequant + bias, C/D layout col=l16, row=lhi*4+reg ----
  const float ascale = __uint_as_float(*maxbits) / 127.0f;
#pragma unroll
  for (int i = 0; i < 8; ++i) {
    const int orow = m0 + wave_m * 128 + i * 16 + lhi * 4;
#pragma unroll
    for (int j = 0; j < 4; ++j) {
      const int ocol = n0 + wave_n * 64 + j * 16 + l16;
      const float wsc = wscale[ocol] * ascale;
      const float bb = bias[ocol];
#pragma unroll
      for (int r = 0; r < 4; ++r) {
        out[(size_t)(orow + r) * N_TOT + ocol] = (float)acc[i][j][r] * wsc + bb;
      }
    }
  }
}

// ---------------------------------------------------------------------------
extern "C" void kernel_launch(void* const* d_in, const int* in_sizes, int n_in,
                              void* d_out, int out_size, void* d_ws, size_t ws_size,
                              hipStream_t stream) {
  const float* x = (const float*)d_in[0];
  const int* w32 = (const int*)d_in[1];        // int8 in reference, int32 on device
  const float* wscale = (const float*)d_in[2];
  const float* smooth = (const float*)d_in[3];
  const float* bias = (const float*)d_in[4];
  float* out = (float*)d_out;

  unsigned int* maxbits = (unsigned int*)d_ws;
  int8_t* xq = (int8_t*)d_ws + (1 << 20);                    // 32 MB
  int8_t* wq8 = xq + (size_t)M_TOT * K_TOT;                  // 16 MB

  hipMemsetAsync(d_ws, 0, 4, stream);  // zero the max accumulator each call

  int nw4 = N_TOT * K_TOT / 4;
  int n4 = M_TOT * K_TOT / 4;
  const int4* w32v = (const int4*)w32;
  int* wq8v = (int*)wq8;
  const float4* smooth4 = (const float4*)smooth;
  const float4* x4 = (const float4*)x;
  int* xqv = (int*)xq;
  void* args[] = {(void*)&w32v, (void*)&wq8v, (void*)&nw4, (void*)&smooth4,
                  (void*)&x4, (void*)&maxbits, (void*)&n4, (void*)&xqv};
  hipLaunchCooperativeKernel((void*)prep_all, dim3(1024), dim3(256), args, 0, stream);

  dim3 grid(N_TOT / BN, M_TOT / BM);
  gemm_i8<<<grid, 512, 0, stream>>>(xq, wq8, maxbits, wscale, bias, out);
}

// Round 10
// 225.917 us; speedup vs baseline: 1.4151x; 1.4151x over previous
//
#include <hip/hip_runtime.h>
#include <stdint.h>

// Problem constants (B=4, S=2048 -> M = 8192 rows)
#define M_TOT 8192
#define N_TOT 4096
#define K_TOT 4096

typedef int v4i __attribute__((ext_vector_type(4)));

// GEMM tile config: 256x256 tile, K-step 64 B, 8 waves (2M x 4N), 512 thr.
#define BM 256
#define BN 256
#define SUB 64
#define NS (K_TOT / SUB)                  // 64 K-step iterations
#define A_SUB (BM * SUB)                  // 16 KB
#define B_SUB (BN * SUB)                  // 16 KB
#define BUF_BYTES (A_SUB + B_SUB)         // 32 KB; x2 buffers = 64 KB LDS

// ---------------------------------------------------------------------------
// Kernel 1: fused pre-pass: pack weight int32->int8 + global max(|x/smooth|).
// (R6 verbatim — measured ~88 us for this + quantize incl. gaps.)
// Grid stride (524288) is a multiple of K/4=1024 -> smooth slice loop-invariant.
// ---------------------------------------------------------------------------
__global__ void prep_reduce(const int4* __restrict__ w32, int* __restrict__ w8,
                            int nw4, const float4* __restrict__ smooth4,
                            const float4* __restrict__ x,
                            unsigned int* __restrict__ maxbits, int nx4) {
  const int stride = gridDim.x * blockDim.x;
  const int g0 = blockIdx.x * blockDim.x + threadIdx.x;
  for (int i = g0; i < nw4; i += stride) {
    int4 v = w32[i];
    w8[i] = (v.x & 0xff) | ((v.y & 0xff) << 8) | ((v.z & 0xff) << 16) | (v.w << 24);
  }
  float4 s = smooth4[g0 & (K_TOT / 4 - 1)];
  const float rx = 1.0f / s.x, ry = 1.0f / s.y, rz = 1.0f / s.z, rw = 1.0f / s.w;
  float m = 0.0f;
  for (int i = g0; i < nx4; i += stride) {
    float4 v = x[i];
    m = fmaxf(m, fabsf(v.x * rx));
    m = fmaxf(m, fabsf(v.y * ry));
    m = fmaxf(m, fabsf(v.z * rz));
    m = fmaxf(m, fabsf(v.w * rw));
  }
#pragma unroll
  for (int off = 32; off; off >>= 1) m = fmaxf(m, __shfl_xor(m, off));
  __shared__ float sm[4];
  if ((threadIdx.x & 63) == 0) sm[threadIdx.x >> 6] = m;
  __syncthreads();
  if (threadIdx.x == 0) {
    float mm = fmaxf(fmaxf(sm[0], sm[1]), fmaxf(sm[2], sm[3]));
    atomicMax(maxbits, __float_as_uint(mm));
  }
}

// ---------------------------------------------------------------------------
// Kernel 2: quantize x -> int8 packed; rinv = (1/s) * (1/d) hoisted per thread
// ---------------------------------------------------------------------------
__global__ void quantize_x(const float4* __restrict__ x,
                           const float4* __restrict__ smooth4,
                           const unsigned int* __restrict__ maxbits,
                           int* __restrict__ xq, int n4) {
  const float d = __uint_as_float(*maxbits) / 127.0f + 1e-5f;
  const float inv = 1.0f / d;
  const int stride = gridDim.x * blockDim.x;
  const int g0 = blockIdx.x * blockDim.x + threadIdx.x;
  float4 s = smooth4[g0 & (K_TOT / 4 - 1)];
  const float rx = inv / s.x, ry = inv / s.y, rz = inv / s.z, rw = inv / s.w;
  for (int i = g0; i < n4; i += stride) {
    float4 v = x[i];
    int q0 = (int)fminf(fmaxf(rintf(v.x * rx), -128.0f), 127.0f);
    int q1 = (int)fminf(fmaxf(rintf(v.y * ry), -128.0f), 127.0f);
    int q2 = (int)fminf(fmaxf(rintf(v.z * rz), -128.0f), 127.0f);
    int q3 = (int)fminf(fmaxf(rintf(v.w * rw), -128.0f), 127.0f);
    xq[i] = (q0 & 0xff) | ((q1 & 0xff) << 8) | ((q2 & 0xff) << 16) | (q3 << 24);
  }
}

// ---------------------------------------------------------------------------
// Kernel 3: int8 GEMM, 256x256 tile, 64-B K-steps, 2x32KB double buffer,
// m201-style 4-phase-per-K-tile role-split schedule (T3+T4+T5 regime).
//
// Per K-tile t (buf = t&1), quadrants of the wave's 128x64 output:
//  P1: ds_read a[0-3],b[0-1] -> bar -> lgkm(0) -> prio1 + 8 MFMA (i0-3,j0-1) -> bar
//  P2: ds_read a[4-7],b[2-3] -> bar -> lgkm(0) -> prio1 + 8 MFMA (i4-7,j0-1) -> bar
//  P3: stage half of tile t+2 (2 gloads) -> prio1 + 8 MFMA (i0-3,j2-3) -> bar
//  P4: stage other half (2 gloads) -> prio1 + 8 MFMA (i4-7,j2-3) -> vmcnt(4) -> bar
//
// Race-freedom:
//  * ALL 12 reads of buf[t&1] are issued in P1/P2; each wave's reads complete
//    before its P2 lgkmcnt(0); P2's post-MFMA barrier makes that global ->
//    staging tile t+2 into buf[t&1] at P3/P4 cannot write under a read.
//  * vmcnt(4) at P4: outstanding = t+2's 4 (P3/P4) + t+1's 4 (prev tile's
//    P3/P4) = 8 -> draining to 4 completes tile t+1; barrier makes it global
//    before iter t+1's P1 reads buf[(t+1)&1]. Induction base: prologue stages
//    tiles 0,1 then vmcnt(4) drains tile 0. vmcnt never 0 in the loop (T4).
//
// LDS swizzle (T2, 64-B rows, 8-lane ds_read_b128 grouping) — MEASURED 0:
//   read slot = (lhi ^ ((l16>>1)&3))*16; stage gcol = ((lane&3)^((lane>>3)&3))*16
// (R5's l16>>2 variant and R7's 32-row variant both measured 1.26e7 — do not
//  touch this pattern without a measured-zero replacement.)
// ---------------------------------------------------------------------------
__global__ __launch_bounds__(512, 2) void gemm_i8(
    const int8_t* __restrict__ Aq,   // [M][K]
    const int8_t* __restrict__ Wt,   // [N][K]
    const unsigned int* __restrict__ maxbits,
    const float* __restrict__ wscale,  // [N]
    const float* __restrict__ bias,    // [N]
    float* __restrict__ out) {         // [M][N]
  __shared__ int8_t lds[2 * BUF_BYTES];

  const int tid = threadIdx.x;
  const int lane = tid & 63;
  const int wid = tid >> 6;      // 0..7
  const int l16 = lane & 15;
  const int lhi = lane >> 4;     // 0..3

  // T1: XCD-aware block swizzle. 512 blocks, 512 % 8 == 0 -> bijective.
  const int flat = blockIdx.y * gridDim.x + blockIdx.x;
  const int swz = (flat & 7) * 64 + (flat >> 3);
  const int m0 = (swz / (N_TOT / BN)) * BM;
  const int n0 = (swz % (N_TOT / BN)) * BN;

  const int wave_m = wid >> 2;   // 0..1  -> 128 rows
  const int wave_n = wid & 3;    // 0..3  -> 64 cols

  // ---- staging: per wave 2 A-chunks + 2 B-chunks, 1 KB each (16 rows x 64 B)
  const int row_l = lane >> 2;                             // row in chunk 0..15
  const int gcol = ((lane & 3) ^ ((lane >> 3) & 3)) << 4;  // pre-swizzled slot
  const int8_t* Abase = Aq + (size_t)m0 * K_TOT;           // uniform
  const int8_t* Bbase = Wt + (size_t)n0 * K_TOT;           // uniform
  int goff[2];
#pragma unroll
  for (int c = 0; c < 2; ++c) {
    int grow = (wid * 2 + c) * 16 + row_l;                 // 0..255
    goff[c] = grow * K_TOT + gcol;
  }

  // stage half c (A chunk c + B chunk c) of tile at byte offset koff
  auto stage_half = [&](int dstbuf, int koff, int c) {
    __builtin_amdgcn_global_load_lds(
        (const __attribute__((address_space(1))) void*)(Abase + goff[c] + koff),
        (__attribute__((address_space(3))) void*)(lds + dstbuf * BUF_BYTES + (wid * 2 + c) * 1024),
        16, 0, 0);
    __builtin_amdgcn_global_load_lds(
        (const __attribute__((address_space(1))) void*)(Bbase + goff[c] + koff),
        (__attribute__((address_space(3))) void*)(lds + dstbuf * BUF_BYTES + A_SUB + (wid * 2 + c) * 1024),
        16, 0, 0);
  };

  // ---- ds_read fragment addressing (swizzled, 64-B rows) ----
  const int slot = (lhi ^ ((l16 >> 1) & 3)) << 4;
  const int aOff = (wave_m * 128 + l16) * SUB + slot;
  const int bOff = (wave_n * 64 + l16) * SUB + slot;

  // ---- prologue: stage tiles 0,1; drain tile 0 ----
  stage_half(0, 0, 0);
  stage_half(0, 0, 1);
  stage_half(1, SUB, 0);
  stage_half(1, SUB, 1);
  asm volatile("s_waitcnt vmcnt(4)" ::: "memory");
  __builtin_amdgcn_s_barrier();
  __builtin_amdgcn_sched_barrier(0);

  v4i acc[8][4] = {};

#pragma unroll 2
  for (int t = 0; t < NS; ++t) {
    const int buf = t & 1;
    const int8_t* Ab = lds + buf * BUF_BYTES;
    const int8_t* Bb = Ab + A_SUB;
    const int ts = ((t + 2 < NS) ? t + 2 : NS - 1) * SUB;

    v4i a[8], b[4];

    // ================= P1: reads a0-3,b0-1; MFMA quadrant (i0-3, j0-1) ====
#pragma unroll
    for (int i = 0; i < 4; ++i) a[i] = *(const v4i*)(Ab + aOff + i * 1024);
#pragma unroll
    for (int j = 0; j < 2; ++j) b[j] = *(const v4i*)(Bb + bOff + j * 1024);
    __builtin_amdgcn_s_barrier();
    asm volatile("s_waitcnt lgkmcnt(0)" ::: "memory");
    __builtin_amdgcn_sched_barrier(0);
    __builtin_amdgcn_s_setprio(1);
#pragma unroll
    for (int i = 0; i < 4; ++i)
#pragma unroll
      for (int j = 0; j < 2; ++j)
        acc[i][j] = __builtin_amdgcn_mfma_i32_16x16x64_i8(a[i], b[j], acc[i][j], 0, 0, 0);
    __builtin_amdgcn_s_setprio(0);
    __builtin_amdgcn_sched_barrier(0);
    __builtin_amdgcn_s_barrier();

    // ================= P2: reads a4-7,b2-3; MFMA quadrant (i4-7, j0-1) ====
#pragma unroll
    for (int i = 4; i < 8; ++i) a[i] = *(const v4i*)(Ab + aOff + i * 1024);
#pragma unroll
    for (int j = 2; j < 4; ++j) b[j] = *(const v4i*)(Bb + bOff + j * 1024);
    __builtin_amdgcn_s_barrier();
    asm volatile("s_waitcnt lgkmcnt(0)" ::: "memory");
    __builtin_amdgcn_sched_barrier(0);
    __builtin_amdgcn_s_setprio(1);
#pragma unroll
    for (int i = 4; i < 8; ++i)
#pragma unroll
      for (int j = 0; j < 2; ++j)
        acc[i][j] = __builtin_amdgcn_mfma_i32_16x16x64_i8(a[i], b[j], acc[i][j], 0, 0, 0);
    __builtin_amdgcn_s_setprio(0);
    __builtin_amdgcn_sched_barrier(0);
    __builtin_amdgcn_s_barrier();

    // ================= P3: stage t+2 half 0; MFMA quadrant (i0-3, j2-3) ===
    stage_half(buf, ts, 0);
    __builtin_amdgcn_sched_barrier(0);
    __builtin_amdgcn_s_setprio(1);
#pragma unroll
    for (int i = 0; i < 4; ++i)
#pragma unroll
      for (int j = 2; j < 4; ++j)
        acc[i][j] = __builtin_amdgcn_mfma_i32_16x16x64_i8(a[i], b[j], acc[i][j], 0, 0, 0);
    __builtin_amdgcn_s_setprio(0);
    __builtin_amdgcn_sched_barrier(0);
    __builtin_amdgcn_s_barrier();

    // ================= P4: stage t+2 half 1; MFMA quadrant (i4-7, j2-3) ===
    stage_half(buf, ts, 1);
    __builtin_amdgcn_sched_barrier(0);
    __builtin_amdgcn_s_setprio(1);
#pragma unroll
    for (int i = 4; i < 8; ++i)
#pragma unroll
      for (int j = 2; j < 4; ++j)
        acc[i][j] = __builtin_amdgcn_mfma_i32_16x16x64_i8(a[i], b[j], acc[i][j], 0, 0, 0);
    __builtin_amdgcn_s_setprio(0);
    __builtin_amdgcn_sched_barrier(0);
    asm volatile("s_waitcnt vmcnt(4)" ::: "memory");
    __builtin_amdgcn_sched_barrier(0);
    __builtin_amdgcn_s_barrier();
    __builtin_amdgcn_sched_barrier(0);
  }

  // drain outstanding DMA before epilogue (last redundant stages)
  asm volatile("s_waitcnt vmcnt(0) lgkmcnt(0)" ::: "memory");

  // ---- epilogue: dequant + bias, C/D layout col=l16, row=lhi*4+reg ----
  const float ascale = __uint_as_float(*maxbits) / 127.0f;
#pragma unroll
  for (int i = 0; i < 8; ++i) {
    const int orow = m0 + wave_m * 128 + i * 16 + lhi * 4;
#pragma unroll
    for (int j = 0; j < 4; ++j) {
      const int ocol = n0 + wave_n * 64 + j * 16 + l16;
      const float wsc = wscale[ocol] * ascale;
      const float bb = bias[ocol];
#pragma unroll
      for (int r = 0; r < 4; ++r) {
        out[(size_t)(orow + r) * N_TOT + ocol] = (float)acc[i][j][r] * wsc + bb;
      }
    }
  }
}

// ---------------------------------------------------------------------------
extern "C" void kernel_launch(void* const* d_in, const int* in_sizes, int n_in,
                              void* d_out, int out_size, void* d_ws, size_t ws_size,
                              hipStream_t stream) {
  const float* x = (const float*)d_in[0];
  const int* w32 = (const int*)d_in[1];        // int8 in reference, int32 on device
  const float* wscale = (const float*)d_in[2];
  const float* smooth = (const float*)d_in[3];
  const float* bias = (const float*)d_in[4];
  float* out = (float*)d_out;

  unsigned int* maxbits = (unsigned int*)d_ws;
  int8_t* xq = (int8_t*)d_ws + (1 << 20);                    // 32 MB
  int8_t* wq8 = xq + (size_t)M_TOT * K_TOT;                  // 16 MB

  hipMemsetAsync(d_ws, 0, 4, stream);  // zero the max accumulator each call

  const int nw4 = N_TOT * K_TOT / 4;
  const int n4 = M_TOT * K_TOT / 4;
  prep_reduce<<<2048, 256, 0, stream>>>((const int4*)w32, (int*)wq8, nw4,
                                        (const float4*)smooth, (const float4*)x,
                                        maxbits, n4);
  quantize_x<<<2048, 256, 0, stream>>>((const float4*)x, (const float4*)smooth,
                                       maxbits, (int*)xq, n4);

  dim3 grid(N_TOT / BN, M_TOT / BM);
  gemm_i8<<<grid, 512, 0, stream>>>(xq, wq8, maxbits, wscale, bias, out);
}

// Round 11
// 204.377 us; speedup vs baseline: 1.5642x; 1.1054x over previous
//
#include <hip/hip_runtime.h>
#include <stdint.h>

// Problem constants (B=4, S=2048 -> M = 8192 rows)
#define M_TOT 8192
#define N_TOT 4096
#define K_TOT 4096

typedef int v4i __attribute__((ext_vector_type(4)));

// GEMM tile config: 256x256 tile, sub-tile K-step = 64 B, 8 waves (2M x 4N)
#define BM 256
#define BN 256
#define SUB 64
#define NS (K_TOT / SUB)                  // 64 sub-tile iterations
#define A_SUB (BM * SUB)                  // 16 KB
#define B_SUB (BN * SUB)                  // 16 KB
#define BUF_BYTES (A_SUB + B_SUB)         // 32 KB; x4 buffers = 128 KB LDS

#define NPREP 2048                        // prep_reduce grid = partials count

// ---------------------------------------------------------------------------
// Kernel 1: pack weight int32->int8 + per-block max(|x/smooth|) -> partials.
// No atomics, no init required (all NPREP entries written every call).
// Grid stride (524288) is a multiple of K/4=1024 -> smooth slice loop-invariant.
// ---------------------------------------------------------------------------
__global__ void prep_reduce(const int4* __restrict__ w32, int* __restrict__ w8,
                            int nw4, const float4* __restrict__ smooth4,
                            const float4* __restrict__ x,
                            float* __restrict__ partials, int nx4) {
  const int stride = gridDim.x * blockDim.x;
  const int g0 = blockIdx.x * blockDim.x + threadIdx.x;
  for (int i = g0; i < nw4; i += stride) {
    int4 v = w32[i];
    w8[i] = (v.x & 0xff) | ((v.y & 0xff) << 8) | ((v.z & 0xff) << 16) | (v.w << 24);
  }
  float4 s = smooth4[g0 & (K_TOT / 4 - 1)];
  const float rx = 1.0f / s.x, ry = 1.0f / s.y, rz = 1.0f / s.z, rw = 1.0f / s.w;
  float m = 0.0f;
  for (int i = g0; i < nx4; i += stride) {
    float4 v = x[i];
    m = fmaxf(m, fabsf(v.x * rx));
    m = fmaxf(m, fabsf(v.y * ry));
    m = fmaxf(m, fabsf(v.z * rz));
    m = fmaxf(m, fabsf(v.w * rw));
  }
#pragma unroll
  for (int off = 32; off; off >>= 1) m = fmaxf(m, __shfl_xor(m, off));
  __shared__ float sm[4];
  if ((threadIdx.x & 63) == 0) sm[threadIdx.x >> 6] = m;
  __syncthreads();
  if (threadIdx.x == 0) {
    partials[blockIdx.x] = fmaxf(fmaxf(sm[0], sm[1]), fmaxf(sm[2], sm[3]));
  }
}

// ---------------------------------------------------------------------------
// Kernel 2: reduce partials (every block, identical result) -> inv scale;
// block 0 stores maxbits for the GEMM epilogue; then quantize x -> int8.
// rinv = (1/s) * inv hoisted per thread (grid stride multiple of K/4).
// ---------------------------------------------------------------------------
__global__ void quantize_x(const float4* __restrict__ x,
                           const float4* __restrict__ smooth4,
                           const float* __restrict__ partials,
                           unsigned int* __restrict__ maxbits,
                           int* __restrict__ xq, int n4) {
  // ---- redundant per-block reduction of the NPREP partials ----
  float m = 0.0f;
  for (int i = threadIdx.x; i < NPREP; i += blockDim.x) m = fmaxf(m, partials[i]);
#pragma unroll
  for (int off = 32; off; off >>= 1) m = fmaxf(m, __shfl_xor(m, off));
  __shared__ float sm[4];
  __shared__ float s_inv;
  if ((threadIdx.x & 63) == 0) sm[threadIdx.x >> 6] = m;
  __syncthreads();
  if (threadIdx.x == 0) {
    float mm = fmaxf(fmaxf(sm[0], sm[1]), fmaxf(sm[2], sm[3]));
    if (blockIdx.x == 0) *maxbits = __float_as_uint(mm);   // for gemm epilogue
    s_inv = 1.0f / (mm / 127.0f + 1e-5f);
  }
  __syncthreads();
  const float inv = s_inv;

  const int stride = gridDim.x * blockDim.x;
  const int g0 = blockIdx.x * blockDim.x + threadIdx.x;
  float4 s = smooth4[g0 & (K_TOT / 4 - 1)];
  const float rx = inv / s.x, ry = inv / s.y, rz = inv / s.z, rw = inv / s.w;
  for (int i = g0; i < n4; i += stride) {
    float4 v = x[i];
    int q0 = (int)fminf(fmaxf(rintf(v.x * rx), -128.0f), 127.0f);
    int q1 = (int)fminf(fmaxf(rintf(v.y * ry), -128.0f), 127.0f);
    int q2 = (int)fminf(fmaxf(rintf(v.z * rz), -128.0f), 127.0f);
    int q3 = (int)fminf(fmaxf(rintf(v.w * rw), -128.0f), 127.0f);
    xq[i] = (q0 & 0xff) | ((q1 & 0xff) << 8) | ((q2 & 0xff) << 16) | (q3 << 24);
  }
}

// ---------------------------------------------------------------------------
// Kernel 3: int8 GEMM — VERIFIED OPTIMUM, byte-for-byte (136.5 us, MfmaUtil
// 44%, SQ_LDS_BANK_CONFLICT == 0). 256x256 tile, 64-B K-sub-tiles, 4-buffer /
// 3-deep counted-vmcnt pipeline, ONE barrier per sub-tile.
//
// Race-freedom (iteration s, reading buf[s&3]):
//   * stage targets buf[(s+3)&3] = buf[(s-1)&3]: reads completed before iter
//     s-1's end barrier (lgkmcnt(0) precedes it). -> no write-under-read.
//   * vmcnt(8) at iter s end: outstanding = 12 (s, s-1, s-2); completing to 8
//     drains the OLDEST 4 = sub-tile s+1's loads; barrier makes that global.
//     Induction base: prologue stages 0,1,2 then vmcnt(8) drains sub-tile 0.
//   * vmcnt never drains to 0 in the loop (T4).
//
// LDS swizzle (T2, 64-B rows, 8-lane ds_read_b128 grouping) — MEASURED 0:
//   read slot = (lhi ^ ((l16>>1)&3))*16; stage gcol = ((lane&3)^((lane>>3)&3))*16
// (R5's l16>>2 variant and R7's 32-row variant both measured 1.26e7 — do not
//  touch this pattern without a measured-zero replacement.)
// ---------------------------------------------------------------------------
__global__ __launch_bounds__(512, 2) void gemm_i8(
    const int8_t* __restrict__ Aq,   // [M][K]
    const int8_t* __restrict__ Wt,   // [N][K]
    const unsigned int* __restrict__ maxbits,
    const float* __restrict__ wscale,  // [N]
    const float* __restrict__ bias,    // [N]
    float* __restrict__ out) {         // [M][N]
  __shared__ int8_t lds[4 * BUF_BYTES];

  const int tid = threadIdx.x;
  const int lane = tid & 63;
  const int wid = tid >> 6;      // 0..7
  const int l16 = lane & 15;
  const int lhi = lane >> 4;     // 0..3

  // T1: XCD-aware block swizzle. 512 blocks, 512 % 8 == 0 -> bijective.
  const int flat = blockIdx.y * gridDim.x + blockIdx.x;
  const int swz = (flat & 7) * 64 + (flat >> 3);
  const int m0 = (swz / (N_TOT / BN)) * BM;
  const int n0 = (swz % (N_TOT / BN)) * BN;

  const int wave_m = wid >> 2;   // 0..1  -> 128 rows
  const int wave_n = wid & 3;    // 0..3  -> 64 cols

  // ---- staging: per wave 2 A-chunks + 2 B-chunks, 1 KB each (16 rows x 64 B)
  const int row_l = lane >> 2;                             // row in chunk 0..15
  const int gcol = ((lane & 3) ^ ((lane >> 3) & 3)) << 4;  // pre-swizzled slot
  const int8_t* Abase = Aq + (size_t)m0 * K_TOT;           // uniform
  const int8_t* Bbase = Wt + (size_t)n0 * K_TOT;           // uniform
  int goff[2];
#pragma unroll
  for (int c = 0; c < 2; ++c) {
    int grow = (wid * 2 + c) * 16 + row_l;                 // 0..255
    goff[c] = grow * K_TOT + gcol;
  }

  auto stage = [&](int dstbuf, int koff) {
#pragma unroll
    for (int c = 0; c < 2; ++c) {
      __builtin_amdgcn_global_load_lds(
          (const __attribute__((address_space(1))) void*)(Abase + goff[c] + koff),
          (__attribute__((address_space(3))) void*)(lds + dstbuf * BUF_BYTES + (wid * 2 + c) * 1024),
          16, 0, 0);
      __builtin_amdgcn_global_load_lds(
          (const __attribute__((address_space(1))) void*)(Bbase + goff[c] + koff),
          (__attribute__((address_space(3))) void*)(lds + dstbuf * BUF_BYTES + A_SUB + (wid * 2 + c) * 1024),
          16, 0, 0);
    }
  };

  // ---- ds_read fragment addressing (swizzled, 64-B rows) ----
  const int slot = (lhi ^ ((l16 >> 1) & 3)) << 4;
  const int aOff = (wave_m * 128 + l16) * SUB + slot;
  const int bOff = (wave_n * 64 + l16) * SUB + slot;

  // ---- prologue: stage sub-tiles 0,1,2; drain sub-tile 0 ----
  stage(0, 0);
  stage(1, SUB);
  stage(2, 2 * SUB);
  asm volatile("s_waitcnt vmcnt(8)" ::: "memory");
  __builtin_amdgcn_s_barrier();
  __builtin_amdgcn_sched_barrier(0);

  v4i acc[8][4] = {};

#pragma unroll 4
  for (int s = 0; s < NS; ++s) {
    const int buf = s & 3;
    const int8_t* Ab = lds + buf * BUF_BYTES;
    const int8_t* Bb = Ab + A_SUB;

    // prefetch sub-tile s+3 into the buffer drained at iter s-1
    const int ts = (s + 3 < NS) ? (s + 3) : (NS - 1);
    stage((s + 3) & 3, ts * SUB);

    // 12 ds_read_b128; compiler-counted lgkmcnt lets MFMA overlap them
    v4i a[8], b[4];
#pragma unroll
    for (int i = 0; i < 8; ++i) a[i] = *(const v4i*)(Ab + aOff + i * 1024);
#pragma unroll
    for (int j = 0; j < 4; ++j) b[j] = *(const v4i*)(Bb + bOff + j * 1024);

    __builtin_amdgcn_s_setprio(1);
#pragma unroll
    for (int i = 0; i < 8; ++i)
#pragma unroll
      for (int j = 0; j < 4; ++j)
        acc[i][j] = __builtin_amdgcn_mfma_i32_16x16x64_i8(a[i], b[j], acc[i][j], 0, 0, 0);
    __builtin_amdgcn_s_setprio(0);
    __builtin_amdgcn_sched_barrier(0);

    asm volatile("s_waitcnt lgkmcnt(0)" ::: "memory");
    asm volatile("s_waitcnt vmcnt(8)" ::: "memory");
    __builtin_amdgcn_sched_barrier(0);
    __builtin_amdgcn_s_barrier();
    __builtin_amdgcn_sched_barrier(0);
  }

  // ---- epilogue: dequant + bias, C/D layout col=l16, row=lhi*4+reg ----
  const float ascale = __uint_as_float(*maxbits) / 127.0f;
#pragma unroll
  for (int i = 0; i < 8; ++i) {
    const int orow = m0 + wave_m * 128 + i * 16 + lhi * 4;
#pragma unroll
    for (int j = 0; j < 4; ++j) {
      const int ocol = n0 + wave_n * 64 + j * 16 + l16;
      const float wsc = wscale[ocol] * ascale;
      const float bb = bias[ocol];
#pragma unroll
      for (int r = 0; r < 4; ++r) {
        out[(size_t)(orow + r) * N_TOT + ocol] = (float)acc[i][j][r] * wsc + bb;
      }
    }
  }
}

// ---------------------------------------------------------------------------
extern "C" void kernel_launch(void* const* d_in, const int* in_sizes, int n_in,
                              void* d_out, int out_size, void* d_ws, size_t ws_size,
                              hipStream_t stream) {
  const float* x = (const float*)d_in[0];
  const int* w32 = (const int*)d_in[1];        // int8 in reference, int32 on device
  const float* wscale = (const float*)d_in[2];
  const float* smooth = (const float*)d_in[3];
  const float* bias = (const float*)d_in[4];
  float* out = (float*)d_out;

  unsigned int* maxbits = (unsigned int*)d_ws;
  float* partials = (float*)((char*)d_ws + 1024);            // NPREP floats
  int8_t* xq = (int8_t*)d_ws + (1 << 20);                    // 32 MB
  int8_t* wq8 = xq + (size_t)M_TOT * K_TOT;                  // 16 MB

  const int nw4 = N_TOT * K_TOT / 4;
  const int n4 = M_TOT * K_TOT / 4;
  prep_reduce<<<NPREP, 256, 0, stream>>>((const int4*)w32, (int*)wq8, nw4,
                                         (const float4*)smooth, (const float4*)x,
                                         partials, n4);
  quantize_x<<<2048, 256, 0, stream>>>((const float4*)x, (const float4*)smooth,
                                       partials, maxbits, (int*)xq, n4);

  dim3 grid(N_TOT / BN, M_TOT / BM);
  gemm_i8<<<grid, 512, 0, stream>>>(xq, wq8, maxbits, wscale, bias, out);
}

// Round 12
// 202.715 us; speedup vs baseline: 1.5770x; 1.0082x over previous
//
#include <hip/hip_runtime.h>
#include <stdint.h>

// Problem constants (B=4, S=2048 -> M = 8192 rows)
#define M_TOT 8192
#define N_TOT 4096
#define K_TOT 4096

typedef int v4i __attribute__((ext_vector_type(4)));

// GEMM tile config: 256x256 tile, sub-tile K-step = 64 B, 8 waves (2M x 4N)
#define BM 256
#define BN 256
#define SUB 64
#define NS (K_TOT / SUB)                  // 64 sub-tile iterations
#define A_SUB (BM * SUB)                  // 16 KB
#define B_SUB (BN * SUB)                  // 16 KB
#define BUF_BYTES (A_SUB + B_SUB)         // 32 KB; x4 buffers = 128 KB LDS

#define NPREP 2048                        // prep_reduce grid = partials count

// ---------------------------------------------------------------------------
// Kernel 1: pack weight int32->int8 + per-block max(|x/smooth|) -> partials.
// No atomics, no init required (all NPREP entries written every call).
// Grid stride (524288) is a multiple of K/4=1024 -> smooth slice loop-invariant.
// ---------------------------------------------------------------------------
__global__ void prep_reduce(const int4* __restrict__ w32, int* __restrict__ w8,
                            int nw4, const float4* __restrict__ smooth4,
                            const float4* __restrict__ x,
                            float* __restrict__ partials, int nx4) {
  const int stride = gridDim.x * blockDim.x;
  const int g0 = blockIdx.x * blockDim.x + threadIdx.x;
  for (int i = g0; i < nw4; i += stride) {
    int4 v = w32[i];
    w8[i] = (v.x & 0xff) | ((v.y & 0xff) << 8) | ((v.z & 0xff) << 16) | (v.w << 24);
  }
  float4 s = smooth4[g0 & (K_TOT / 4 - 1)];
  const float rx = 1.0f / s.x, ry = 1.0f / s.y, rz = 1.0f / s.z, rw = 1.0f / s.w;
  float m = 0.0f;
  for (int i = g0; i < nx4; i += stride) {
    float4 v = x[i];
    m = fmaxf(m, fabsf(v.x * rx));
    m = fmaxf(m, fabsf(v.y * ry));
    m = fmaxf(m, fabsf(v.z * rz));
    m = fmaxf(m, fabsf(v.w * rw));
  }
#pragma unroll
  for (int off = 32; off; off >>= 1) m = fmaxf(m, __shfl_xor(m, off));
  __shared__ float sm[4];
  if ((threadIdx.x & 63) == 0) sm[threadIdx.x >> 6] = m;
  __syncthreads();
  if (threadIdx.x == 0) {
    partials[blockIdx.x] = fmaxf(fmaxf(sm[0], sm[1]), fmaxf(sm[2], sm[3]));
  }
}

// ---------------------------------------------------------------------------
// Kernel 2: reduce partials (every block, identical result) -> inv scale;
// block 0 stores maxbits for the GEMM epilogue; then quantize x -> int8.
// rinv = (1/s) * inv hoisted per thread (grid stride multiple of K/4).
// ---------------------------------------------------------------------------
__global__ void quantize_x(const float4* __restrict__ x,
                           const float4* __restrict__ smooth4,
                           const float* __restrict__ partials,
                           unsigned int* __restrict__ maxbits,
                           int* __restrict__ xq, int n4) {
  // ---- redundant per-block reduction of the NPREP partials ----
  float m = 0.0f;
  for (int i = threadIdx.x; i < NPREP; i += blockDim.x) m = fmaxf(m, partials[i]);
#pragma unroll
  for (int off = 32; off; off >>= 1) m = fmaxf(m, __shfl_xor(m, off));
  __shared__ float sm[4];
  __shared__ float s_inv;
  if ((threadIdx.x & 63) == 0) sm[threadIdx.x >> 6] = m;
  __syncthreads();
  if (threadIdx.x == 0) {
    float mm = fmaxf(fmaxf(sm[0], sm[1]), fmaxf(sm[2], sm[3]));
    if (blockIdx.x == 0) *maxbits = __float_as_uint(mm);   // for gemm epilogue
    s_inv = 1.0f / (mm / 127.0f + 1e-5f);
  }
  __syncthreads();
  const float inv = s_inv;

  const int stride = gridDim.x * blockDim.x;
  const int g0 = blockIdx.x * blockDim.x + threadIdx.x;
  float4 s = smooth4[g0 & (K_TOT / 4 - 1)];
  const float rx = inv / s.x, ry = inv / s.y, rz = inv / s.z, rw = inv / s.w;
  for (int i = g0; i < n4; i += stride) {
    float4 v = x[i];
    int q0 = (int)fminf(fmaxf(rintf(v.x * rx), -128.0f), 127.0f);
    int q1 = (int)fminf(fmaxf(rintf(v.y * ry), -128.0f), 127.0f);
    int q2 = (int)fminf(fmaxf(rintf(v.z * rz), -128.0f), 127.0f);
    int q3 = (int)fminf(fmaxf(rintf(v.w * rw), -128.0f), 127.0f);
    xq[i] = (q0 & 0xff) | ((q1 & 0xff) << 8) | ((q2 & 0xff) << 16) | (q3 << 24);
  }
}

// ---------------------------------------------------------------------------
// Kernel 3: int8 GEMM — R6 structure (verified 136.5 us / 44% / 0 conflicts)
// with TWO scheduling-only changes:
//  (1) ds_read order b0-3 FIRST, then a0-7: first MFMA group (i=0, j=0..3)
//      is gated on read #5 instead of read #9; each next group unlocks per
//      single a-read -> ladder of counted lgkmcnt waits, MFMA overlaps drain.
//  (2) stage() issued AFTER the ds_reads: DMA address VALU no longer delays
//      read issue at barrier release. (Position within the iteration is
//      irrelevant to the race argument below.)
//
// Race-freedom (iteration s, reading buf[s&3]):
//   * stage targets buf[(s+3)&3] = buf[(s-1)&3]: reads completed before iter
//     s-1's end barrier (lgkmcnt(0) precedes it). -> no write-under-read.
//   * vmcnt(8) at iter s end: outstanding <= 12 (stages issued at s, s-1,
//     s-2); completing to 8 drains the OLDEST 4 = sub-tile s+1's loads;
//     barrier makes that global. Induction base: prologue stages 0,1,2 then
//     vmcnt(8) drains sub-tile 0. vmcnt never 0 in the loop (T4).
//
// LDS swizzle (T2, 64-B rows) — MEASURED 0 CONFLICTS, do not modify:
//   read slot = (lhi ^ ((l16>>1)&3))*16; stage gcol = ((lane&3)^((lane>>3)&3))*16
// ---------------------------------------------------------------------------
__global__ __launch_bounds__(512, 2) void gemm_i8(
    const int8_t* __restrict__ Aq,   // [M][K]
    const int8_t* __restrict__ Wt,   // [N][K]
    const unsigned int* __restrict__ maxbits,
    const float* __restrict__ wscale,  // [N]
    const float* __restrict__ bias,    // [N]
    float* __restrict__ out) {         // [M][N]
  __shared__ int8_t lds[4 * BUF_BYTES];

  const int tid = threadIdx.x;
  const int lane = tid & 63;
  const int wid = tid >> 6;      // 0..7
  const int l16 = lane & 15;
  const int lhi = lane >> 4;     // 0..3

  // T1: XCD-aware block swizzle. 512 blocks, 512 % 8 == 0 -> bijective.
  const int flat = blockIdx.y * gridDim.x + blockIdx.x;
  const int swz = (flat & 7) * 64 + (flat >> 3);
  const int m0 = (swz / (N_TOT / BN)) * BM;
  const int n0 = (swz % (N_TOT / BN)) * BN;

  const int wave_m = wid >> 2;   // 0..1  -> 128 rows
  const int wave_n = wid & 3;    // 0..3  -> 64 cols

  // ---- staging: per wave 2 A-chunks + 2 B-chunks, 1 KB each (16 rows x 64 B)
  const int row_l = lane >> 2;                             // row in chunk 0..15
  const int gcol = ((lane & 3) ^ ((lane >> 3) & 3)) << 4;  // pre-swizzled slot
  const int8_t* Abase = Aq + (size_t)m0 * K_TOT;           // uniform
  const int8_t* Bbase = Wt + (size_t)n0 * K_TOT;           // uniform
  int goff[2];
#pragma unroll
  for (int c = 0; c < 2; ++c) {
    int grow = (wid * 2 + c) * 16 + row_l;                 // 0..255
    goff[c] = grow * K_TOT + gcol;
  }

  auto stage = [&](int dstbuf, int koff) {
#pragma unroll
    for (int c = 0; c < 2; ++c) {
      __builtin_amdgcn_global_load_lds(
          (const __attribute__((address_space(1))) void*)(Abase + goff[c] + koff),
          (__attribute__((address_space(3))) void*)(lds + dstbuf * BUF_BYTES + (wid * 2 + c) * 1024),
          16, 0, 0);
      __builtin_amdgcn_global_load_lds(
          (const __attribute__((address_space(1))) void*)(Bbase + goff[c] + koff),
          (__attribute__((address_space(3))) void*)(lds + dstbuf * BUF_BYTES + A_SUB + (wid * 2 + c) * 1024),
          16, 0, 0);
    }
  };

  // ---- ds_read fragment addressing (swizzled, 64-B rows) ----
  const int slot = (lhi ^ ((l16 >> 1) & 3)) << 4;
  const int aOff = (wave_m * 128 + l16) * SUB + slot;
  const int bOff = (wave_n * 64 + l16) * SUB + slot;

  // ---- prologue: stage sub-tiles 0,1,2; drain sub-tile 0 ----
  stage(0, 0);
  stage(1, SUB);
  stage(2, 2 * SUB);
  asm volatile("s_waitcnt vmcnt(8)" ::: "memory");
  __builtin_amdgcn_s_barrier();
  __builtin_amdgcn_sched_barrier(0);

  v4i acc[8][4] = {};

#pragma unroll 4
  for (int s = 0; s < NS; ++s) {
    const int buf = s & 3;
    const int8_t* Ab = lds + buf * BUF_BYTES;
    const int8_t* Bb = Ab + A_SUB;

    // 12 ds_read_b128 — b's FIRST so MFMA group 0 is eligible after 5 reads
    v4i a[8], b[4];
#pragma unroll
    for (int j = 0; j < 4; ++j) b[j] = *(const v4i*)(Bb + bOff + j * 1024);
#pragma unroll
    for (int i = 0; i < 8; ++i) a[i] = *(const v4i*)(Ab + aOff + i * 1024);

    // prefetch sub-tile s+3 into the buffer drained at iter s-1
    const int ts = (s + 3 < NS) ? (s + 3) : (NS - 1);
    stage((s + 3) & 3, ts * SUB);

    __builtin_amdgcn_s_setprio(1);
#pragma unroll
    for (int i = 0; i < 8; ++i)
#pragma unroll
      for (int j = 0; j < 4; ++j)
        acc[i][j] = __builtin_amdgcn_mfma_i32_16x16x64_i8(a[i], b[j], acc[i][j], 0, 0, 0);
    __builtin_amdgcn_s_setprio(0);
    __builtin_amdgcn_sched_barrier(0);

    asm volatile("s_waitcnt lgkmcnt(0)" ::: "memory");
    asm volatile("s_waitcnt vmcnt(8)" ::: "memory");
    __builtin_amdgcn_sched_barrier(0);
    __builtin_amdgcn_s_barrier();
    __builtin_amdgcn_sched_barrier(0);
  }

  // ---- epilogue: dequant + bias, C/D layout col=l16, row=lhi*4+reg ----
  const float ascale = __uint_as_float(*maxbits) / 127.0f;
#pragma unroll
  for (int i = 0; i < 8; ++i) {
    const int orow = m0 + wave_m * 128 + i * 16 + lhi * 4;
#pragma unroll
    for (int j = 0; j < 4; ++j) {
      const int ocol = n0 + wave_n * 64 + j * 16 + l16;
      const float wsc = wscale[ocol] * ascale;
      const float bb = bias[ocol];
#pragma unroll
      for (int r = 0; r < 4; ++r) {
        out[(size_t)(orow + r) * N_TOT + ocol] = (float)acc[i][j][r] * wsc + bb;
      }
    }
  }
}

// ---------------------------------------------------------------------------
extern "C" void kernel_launch(void* const* d_in, const int* in_sizes, int n_in,
                              void* d_out, int out_size, void* d_ws, size_t ws_size,
                              hipStream_t stream) {
  const float* x = (const float*)d_in[0];
  const int* w32 = (const int*)d_in[1];        // int8 in reference, int32 on device
  const float* wscale = (const float*)d_in[2];
  const float* smooth = (const float*)d_in[3];
  const float* bias = (const float*)d_in[4];
  float* out = (float*)d_out;

  unsigned int* maxbits = (unsigned int*)d_ws;
  float* partials = (float*)((char*)d_ws + 1024);            // NPREP floats
  int8_t* xq = (int8_t*)d_ws + (1 << 20);                    // 32 MB
  int8_t* wq8 = xq + (size_t)M_TOT * K_TOT;                  // 16 MB

  const int nw4 = N_TOT * K_TOT / 4;
  const int n4 = M_TOT * K_TOT / 4;
  prep_reduce<<<NPREP, 256, 0, stream>>>((const int4*)w32, (int*)wq8, nw4,
                                         (const float4*)smooth, (const float4*)x,
                                         partials, n4);
  quantize_x<<<2048, 256, 0, stream>>>((const float4*)x, (const float4*)smooth,
                                       partials, maxbits, (int*)xq, n4);

  dim3 grid(N_TOT / BN, M_TOT / BM);
  gemm_i8<<<grid, 512, 0, stream>>>(xq, wq8, maxbits, wscale, bias, out);
}